// Round 1
// baseline (4074.514 us; speedup 1.0000x reference)
//
#include <hip/hip_runtime.h>
#include <stdint.h>

#define N_NODES  (1u << 20)      // 1048576
#define N_EDGES  (1u << 24)      // 16777216
#define N_GRAPHS 64
#define CHUNK    (N_NODES / N_GRAPHS)  // 16384
#define K_HOPS   4

// ---------------------------------------------------------------------------
// Detect edge_index element width. Reference dtype is int64, but the harness
// may deliver int32. For little-endian int64 with values < 2^20, every odd
// u32 word is 0. For int32, odd words are random node indices (~0 prob all 0).
// flag[0] = 1 -> int64 layout, 0 -> int32 layout.
__global__ void detect_kernel(const uint32_t* __restrict__ ei, int* __restrict__ flag) {
    __shared__ int any_nz;
    if (threadIdx.x == 0) any_nz = 0;
    __syncthreads();
    int nz = 0;
    for (int i = threadIdx.x; i < 32768; i += blockDim.x)
        nz |= (ei[2 * i + 1] != 0u);
    if (nz) atomicOr(&any_nz, 1);
    __syncthreads();
    if (threadIdx.x == 0) flag[0] = any_nz ? 0 : 1;
}

__global__ void zero_int_kernel(int* __restrict__ p) {
    int i = blockIdx.x * blockDim.x + threadIdx.x;
    p[i] = 0;
}

__device__ __forceinline__ int load_idx(const void* ei, int is64, size_t pos) {
    if (is64) return (int)((const unsigned long long*)ei)[pos];
    return ((const int*)ei)[pos];
}

// deg[v] = number of edges with col == v  (self-loop added later as +1)
__global__ void count_kernel(const void* __restrict__ ei, const int* __restrict__ flag,
                             int* __restrict__ deg) {
    int e = blockIdx.x * blockDim.x + threadIdx.x;
    int is64 = flag[0];
    int c = load_idx(ei, is64, (size_t)N_EDGES + (size_t)e);
    atomicAdd(&deg[c], 1);
}

__global__ void dinv_kernel(const int* __restrict__ deg, float* __restrict__ dinv) {
    int v = blockIdx.x * blockDim.x + threadIdx.x;
    dinv[v] = (float)(1.0 / sqrt((double)(deg[v] + 1)));
}

// First hop prep: z[v] = dinv[v]*x[v]; acc[v] = z[v]  (self-loop term included)
__global__ void prep_first_kernel(const float* __restrict__ x, const float* __restrict__ dinv,
                                  float* __restrict__ z, float* __restrict__ acc) {
    int v = blockIdx.x * blockDim.x + threadIdx.x;
    float t = dinv[v] * x[v];
    z[v] = t;
    acc[v] = t;
}

// Mid hop prep: x_prev[v] = dinv[v]*acc[v]; z[v] = dinv[v]*x_prev[v] = dinv^2*acc
__global__ void prep_mid_kernel(const float* __restrict__ dinv,
                                float* __restrict__ z, float* __restrict__ acc) {
    int v = blockIdx.x * blockDim.x + threadIdx.x;
    float d = dinv[v];
    float t = d * d * acc[v];
    z[v] = t;
    acc[v] = t;
}

// Edge push: acc[col] += z[row]
__global__ void push_kernel(const void* __restrict__ ei, const int* __restrict__ flag,
                            const float* __restrict__ z, float* __restrict__ acc) {
    int e = blockIdx.x * blockDim.x + threadIdx.x;
    int is64 = flag[0];
    int r, c;
    if (is64) {
        const unsigned long long* p = (const unsigned long long*)ei;
        r = (int)p[e];
        c = (int)p[(size_t)N_EDGES + (size_t)e];
    } else {
        const int* p = (const int*)ei;
        r = p[e];
        c = p[(size_t)N_EDGES + (size_t)e];
    }
    __hip_atomic_fetch_add(&acc[c], z[r], __ATOMIC_RELAXED, __HIP_MEMORY_SCOPE_AGENT);
}

// Pool: out[g] = W * mean_{v in chunk g}(dinv[v]*acc[v]) + b
__global__ void pool_kernel(const float* __restrict__ dinv, const float* __restrict__ acc,
                            const float* __restrict__ W, const float* __restrict__ b,
                            float* __restrict__ out) {
    __shared__ double sdata[256];
    int g = blockIdx.x;
    int base = g * CHUNK;
    double s = 0.0;
    for (int i = threadIdx.x; i < CHUNK; i += 256) {
        int v = base + i;
        s += (double)(dinv[v] * acc[v]);
    }
    sdata[threadIdx.x] = s;
    __syncthreads();
    for (int off = 128; off > 0; off >>= 1) {
        if (threadIdx.x < off) sdata[threadIdx.x] += sdata[threadIdx.x + off];
        __syncthreads();
    }
    if (threadIdx.x == 0)
        out[g] = (float)((double)W[0] * (sdata[0] / (double)CHUNK) + (double)b[0]);
}

extern "C" void kernel_launch(void* const* d_in, const int* in_sizes, int n_in,
                              void* d_out, int out_size, void* d_ws, size_t ws_size,
                              hipStream_t stream) {
    const float* x = (const float*)d_in[0];
    const void*  ei = d_in[1];
    const float* W = (const float*)d_in[2];
    const float* b = (const float*)d_in[3];
    float* out = (float*)d_out;

    char* ws = (char*)d_ws;
    int*   flag = (int*)ws;                                   // 256 B
    float* dinv = (float*)(ws + 256);                         // 4 MB
    float* za   = (float*)(ws + 256 + 4ull  * N_NODES);       // 4 MB (z)
    float* zb   = (float*)(ws + 256 + 8ull  * N_NODES);       // 4 MB (acc)
    int*   deg  = (int*)  (ws + 256 + 12ull * N_NODES);       // 4 MB

    const int TB = 256;
    detect_kernel<<<1, TB, 0, stream>>>((const uint32_t*)ei, flag);
    zero_int_kernel<<<N_NODES / TB, TB, 0, stream>>>(deg);
    count_kernel<<<N_EDGES / TB, TB, 0, stream>>>(ei, flag, deg);
    dinv_kernel<<<N_NODES / TB, TB, 0, stream>>>(deg, dinv);

    prep_first_kernel<<<N_NODES / TB, TB, 0, stream>>>(x, dinv, za, zb);
    push_kernel<<<N_EDGES / TB, TB, 0, stream>>>(ei, flag, za, zb);
    for (int h = 1; h < K_HOPS; ++h) {
        prep_mid_kernel<<<N_NODES / TB, TB, 0, stream>>>(dinv, za, zb);
        push_kernel<<<N_EDGES / TB, TB, 0, stream>>>(ei, flag, za, zb);
    }

    pool_kernel<<<N_GRAPHS, TB, 0, stream>>>(dinv, zb, W, b, out);
}

// Round 2
// 2505.627 us; speedup vs baseline: 1.6261x; 1.6261x over previous
//
#include <hip/hip_runtime.h>
#include <stdint.h>

#define N_NODES  (1u << 20)      // 1048576
#define N_EDGES  (1u << 24)      // 16777216
#define N_GRAPHS 64
#define CHUNK    (N_NODES / N_GRAPHS)  // 16384
#define K_HOPS   4

// ---------------------------------------------------------------------------
// Edge dtype detection: int64 little-endian with values < 2^20 has all-zero
// odd u32 words; int32 has random indices there. flag[0]=1 -> int64.
__global__ void detect_kernel(const uint32_t* __restrict__ ei, int* __restrict__ flag) {
    __shared__ int any_nz;
    if (threadIdx.x == 0) any_nz = 0;
    __syncthreads();
    int nz = 0;
    for (int i = threadIdx.x; i < 32768; i += blockDim.x)
        nz |= (ei[2 * i + 1] != 0u);
    if (nz) atomicOr(&any_nz, 1);
    __syncthreads();
    if (threadIdx.x == 0) flag[0] = any_nz ? 0 : 1;
}

__global__ void zero_int_kernel(int* __restrict__ p) {
    int i = blockIdx.x * blockDim.x + threadIdx.x;
    p[i] = 0;
}

__device__ __forceinline__ int load_idx(const void* ei, int is64, size_t pos) {
    if (is64) return (int)((const unsigned long long*)ei)[pos];
    return ((const int*)ei)[pos];
}

// rank[e] = old count of deg[col[e]]  (single atomic pass gives count + position)
__global__ void count_rank_kernel(const void* __restrict__ ei, const int* __restrict__ flag,
                                  int* __restrict__ deg, int* __restrict__ rank) {
    int e = blockIdx.x * blockDim.x + threadIdx.x;
    int is64 = flag[0];
    int c = load_idx(ei, is64, (size_t)N_EDGES + (size_t)e);
    rank[e] = atomicAdd(&deg[c], 1);
}

__global__ void dinv_kernel(const int* __restrict__ deg, float* __restrict__ dinv) {
    int v = blockIdx.x * blockDim.x + threadIdx.x;
    dinv[v] = (float)(1.0 / sqrt((double)(deg[v] + 1)));  // +1 self loop
}

// ---------------- exclusive scan of deg[1M] -> offs[1M+1] -------------------
// Phase 1: per-block (1024 elems) local exclusive scan into offs, block sum out.
__global__ void scan_local_kernel(const int* __restrict__ deg, int* __restrict__ offs,
                                  int* __restrict__ bsum) {
    __shared__ int sh[256];
    int b = blockIdx.x, t = threadIdx.x;
    int idx = b * 1024 + t * 4;
    int a0 = deg[idx], a1 = deg[idx + 1], a2 = deg[idx + 2], a3 = deg[idx + 3];
    int s = a0 + a1 + a2 + a3;
    sh[t] = s;
    __syncthreads();
    for (int off = 1; off < 256; off <<= 1) {
        int v = (t >= off) ? sh[t - off] : 0;
        __syncthreads();
        sh[t] += v;
        __syncthreads();
    }
    int eb = sh[t] - s;  // exclusive base for this thread
    offs[idx]     = eb;
    offs[idx + 1] = eb + a0;
    offs[idx + 2] = eb + a0 + a1;
    offs[idx + 3] = eb + a0 + a1 + a2;
    if (t == 255) bsum[b] = sh[255];
}

// Phase 2: single block scans 1024 block sums -> exclusive bbase, total at [1024].
__global__ void scan_bsums_kernel(const int* __restrict__ bsum, int* __restrict__ bbase) {
    __shared__ int sh[256];
    int t = threadIdx.x;
    int idx = t * 4;
    int a0 = bsum[idx], a1 = bsum[idx + 1], a2 = bsum[idx + 2], a3 = bsum[idx + 3];
    int s = a0 + a1 + a2 + a3;
    sh[t] = s;
    __syncthreads();
    for (int off = 1; off < 256; off <<= 1) {
        int v = (t >= off) ? sh[t - off] : 0;
        __syncthreads();
        sh[t] += v;
        __syncthreads();
    }
    int eb = sh[t] - s;
    bbase[idx]     = eb;
    bbase[idx + 1] = eb + a0;
    bbase[idx + 2] = eb + a0 + a1;
    bbase[idx + 3] = eb + a0 + a1 + a2;
    if (t == 255) bbase[1024] = sh[255];
}

// Phase 3: add block bases; write sentinel offs[N].
__global__ void scan_add_kernel(int* __restrict__ offs, const int* __restrict__ bbase) {
    int i = blockIdx.x * blockDim.x + threadIdx.x;
    offs[i] += bbase[i >> 10];
    if (i == 0) offs[N_NODES] = bbase[1024];
}

// Scatter rows into CSR order (no atomics: position = offs[c] + rank[e]).
__global__ void scatter_kernel(const void* __restrict__ ei, const int* __restrict__ flag,
                               const int* __restrict__ offs, const int* __restrict__ rank,
                               int* __restrict__ rows_sorted) {
    int e = blockIdx.x * blockDim.x + threadIdx.x;
    int is64 = flag[0];
    int r, c;
    if (is64) {
        const unsigned long long* p = (const unsigned long long*)ei;
        r = (int)p[e];
        c = (int)p[(size_t)N_EDGES + (size_t)e];
    } else {
        const int* p = (const int*)ei;
        r = p[e];
        c = p[(size_t)N_EDGES + (size_t)e];
    }
    rows_sorted[offs[c] + rank[e]] = r;
}

// z0 = dinv * x
__global__ void prep_first_kernel(const float* __restrict__ x, const float* __restrict__ dinv,
                                  float* __restrict__ z) {
    int v = blockIdx.x * blockDim.x + threadIdx.x;
    z[v] = dinv[v] * x[v];
}

// Pull hop: t[v] = z[v] + sum_{u->v} z[u];  out = mode ? d^2*t (z_next) : d*t (x_final)
__global__ void pull_kernel(const int* __restrict__ offs, const int* __restrict__ rows,
                            const float* __restrict__ z, const float* __restrict__ dinv,
                            float* __restrict__ out, int mode) {
    int v = blockIdx.x * blockDim.x + threadIdx.x;
    int s = offs[v], e = offs[v + 1];
    float sum = z[v];
    for (int i = s; i < e; ++i) sum += z[rows[i]];
    float d = dinv[v];
    out[v] = mode ? d * d * sum : d * sum;
}

// out[g] = W * mean_{chunk g}(xf) + b
__global__ void pool_kernel(const float* __restrict__ xf,
                            const float* __restrict__ W, const float* __restrict__ b,
                            float* __restrict__ out) {
    __shared__ double sdata[256];
    int g = blockIdx.x;
    int base = g * CHUNK;
    double s = 0.0;
    for (int i = threadIdx.x; i < CHUNK; i += 256) s += (double)xf[base + i];
    sdata[threadIdx.x] = s;
    __syncthreads();
    for (int off = 128; off > 0; off >>= 1) {
        if (threadIdx.x < off) sdata[threadIdx.x] += sdata[threadIdx.x + off];
        __syncthreads();
    }
    if (threadIdx.x == 0)
        out[g] = (float)((double)W[0] * (sdata[0] / (double)CHUNK) + (double)b[0]);
}

// ---------------- fallback (push, atomics) for small ws ---------------------
__global__ void count_kernel(const void* __restrict__ ei, const int* __restrict__ flag,
                             int* __restrict__ deg) {
    int e = blockIdx.x * blockDim.x + threadIdx.x;
    int is64 = flag[0];
    int c = load_idx(ei, is64, (size_t)N_EDGES + (size_t)e);
    atomicAdd(&deg[c], 1);
}

__global__ void prep_first2_kernel(const float* __restrict__ x, const float* __restrict__ dinv,
                                   float* __restrict__ z, float* __restrict__ acc) {
    int v = blockIdx.x * blockDim.x + threadIdx.x;
    float t = dinv[v] * x[v];
    z[v] = t;
    acc[v] = t;
}

__global__ void prep_mid_kernel(const float* __restrict__ dinv,
                                float* __restrict__ z, float* __restrict__ acc) {
    int v = blockIdx.x * blockDim.x + threadIdx.x;
    float d = dinv[v];
    float t = d * d * acc[v];
    z[v] = t;
    acc[v] = t;
}

__global__ void push_kernel(const void* __restrict__ ei, const int* __restrict__ flag,
                            const float* __restrict__ z, float* __restrict__ acc) {
    int e = blockIdx.x * blockDim.x + threadIdx.x;
    int is64 = flag[0];
    int r, c;
    if (is64) {
        const unsigned long long* p = (const unsigned long long*)ei;
        r = (int)p[e];
        c = (int)p[(size_t)N_EDGES + (size_t)e];
    } else {
        const int* p = (const int*)ei;
        r = p[e];
        c = p[(size_t)N_EDGES + (size_t)e];
    }
    __hip_atomic_fetch_add(&acc[c], z[r], __ATOMIC_RELAXED, __HIP_MEMORY_SCOPE_AGENT);
}

__global__ void final_scale_kernel(const float* __restrict__ dinv,
                                   const float* __restrict__ acc, float* __restrict__ xf) {
    int v = blockIdx.x * blockDim.x + threadIdx.x;
    xf[v] = dinv[v] * acc[v];
}

extern "C" void kernel_launch(void* const* d_in, const int* in_sizes, int n_in,
                              void* d_out, int out_size, void* d_ws, size_t ws_size,
                              hipStream_t stream) {
    const float* x = (const float*)d_in[0];
    const void*  ei = d_in[1];
    const float* W = (const float*)d_in[2];
    const float* b = (const float*)d_in[3];
    float* out = (float*)d_out;

    char* ws = (char*)d_ws;
    const size_t MB4 = 4ull << 20;
    size_t off_flag  = 0;
    size_t off_deg   = 256;
    size_t off_offs  = off_deg + MB4;
    size_t off_bsum  = off_offs + MB4 + 4096;
    size_t off_bbase = off_bsum + 8192;
    size_t off_dinv  = off_bbase + 8192;
    size_t off_za    = off_dinv + MB4;
    size_t off_zb    = off_za + MB4;
    size_t off_rank  = off_zb + MB4;
    size_t off_rows  = off_rank + (64ull << 20);
    size_t needed    = off_rows + (64ull << 20);

    const int TB = 256;

    if (ws_size >= needed) {
        int*   flag = (int*)(ws + off_flag);
        int*   deg  = (int*)(ws + off_deg);
        int*   offs = (int*)(ws + off_offs);
        int*   bsum = (int*)(ws + off_bsum);
        int*   bbase= (int*)(ws + off_bbase);
        float* dinv = (float*)(ws + off_dinv);
        float* za   = (float*)(ws + off_za);
        float* zb   = (float*)(ws + off_zb);
        int*   rank = (int*)(ws + off_rank);
        int*   rows = (int*)(ws + off_rows);

        detect_kernel<<<1, TB, 0, stream>>>((const uint32_t*)ei, flag);
        zero_int_kernel<<<N_NODES / TB, TB, 0, stream>>>(deg);
        count_rank_kernel<<<N_EDGES / TB, TB, 0, stream>>>(ei, flag, deg, rank);
        dinv_kernel<<<N_NODES / TB, TB, 0, stream>>>(deg, dinv);

        scan_local_kernel<<<N_NODES / 1024, TB, 0, stream>>>(deg, offs, bsum);
        scan_bsums_kernel<<<1, TB, 0, stream>>>(bsum, bbase);
        scan_add_kernel<<<N_NODES / TB, TB, 0, stream>>>(offs, bbase);

        scatter_kernel<<<N_EDGES / TB, TB, 0, stream>>>(ei, flag, offs, rank, rows);

        prep_first_kernel<<<N_NODES / TB, TB, 0, stream>>>(x, dinv, za);
        pull_kernel<<<N_NODES / TB, TB, 0, stream>>>(offs, rows, za, dinv, zb, 1);
        pull_kernel<<<N_NODES / TB, TB, 0, stream>>>(offs, rows, zb, dinv, za, 1);
        pull_kernel<<<N_NODES / TB, TB, 0, stream>>>(offs, rows, za, dinv, zb, 1);
        pull_kernel<<<N_NODES / TB, TB, 0, stream>>>(offs, rows, zb, dinv, za, 0);

        pool_kernel<<<N_GRAPHS, TB, 0, stream>>>(za, W, b, out);
    } else {
        // Fallback: push-based with atomics (round-1 structure).
        int*   flag = (int*)ws;
        float* dinv = (float*)(ws + 256);
        float* za   = (float*)(ws + 256 + MB4);
        float* zb   = (float*)(ws + 256 + 2 * MB4);
        int*   deg  = (int*)(ws + 256 + 3 * MB4);

        detect_kernel<<<1, TB, 0, stream>>>((const uint32_t*)ei, flag);
        zero_int_kernel<<<N_NODES / TB, TB, 0, stream>>>(deg);
        count_kernel<<<N_EDGES / TB, TB, 0, stream>>>(ei, flag, deg);
        dinv_kernel<<<N_NODES / TB, TB, 0, stream>>>(deg, dinv);

        prep_first2_kernel<<<N_NODES / TB, TB, 0, stream>>>(x, dinv, za, zb);
        push_kernel<<<N_EDGES / TB, TB, 0, stream>>>(ei, flag, za, zb);
        for (int h = 1; h < K_HOPS; ++h) {
            prep_mid_kernel<<<N_NODES / TB, TB, 0, stream>>>(dinv, za, zb);
            push_kernel<<<N_EDGES / TB, TB, 0, stream>>>(ei, flag, za, zb);
        }
        final_scale_kernel<<<N_NODES / TB, TB, 0, stream>>>(dinv, zb, za);
        pool_kernel<<<N_GRAPHS, TB, 0, stream>>>(za, W, b, out);
    }
}

// Round 3
// 1037.136 us; speedup vs baseline: 3.9286x; 2.4159x over previous
//
#include <hip/hip_runtime.h>
#include <stdint.h>

#define N_NODES  (1u << 20)      // 1048576
#define N_EDGES  (1u << 24)      // 16777216
#define N_GRAPHS 64
#define CHUNK    (N_NODES / N_GRAPHS)  // 16384
#define K_HOPS   4

#define NBUCKET  1024            // column buckets
#define CPB      1024            // cols per bucket
#define NBLK     512             // blocks for hist/scatter
#define EPB      (N_EDGES / NBLK)  // 32768 edges per block

// ---------------------------------------------------------------------------
// Edge dtype detection: int64 little-endian with values < 2^20 has all-zero
// odd u32 words; int32 has random indices there. flag[0]=1 -> int64.
__global__ void detect_kernel(const uint32_t* __restrict__ ei, int* __restrict__ flag) {
    __shared__ int any_nz;
    if (threadIdx.x == 0) any_nz = 0;
    __syncthreads();
    int nz = 0;
    for (int i = threadIdx.x; i < 32768; i += blockDim.x)
        nz |= (ei[2 * i + 1] != 0u);
    if (nz) atomicOr(&any_nz, 1);
    __syncthreads();
    if (threadIdx.x == 0) flag[0] = any_nz ? 0 : 1;
}

// ---------------------------------------------------------------------------
// Phase A1: per-block LDS histogram of column buckets.
// bhist layout bucket-major: bhist[b * NBLK + blk]
__global__ void bucket_hist_kernel(const void* __restrict__ ei, const int* __restrict__ flag,
                                   int* __restrict__ bhist) {
    __shared__ int h[NBUCKET];
    int blk = blockIdx.x, tid = threadIdx.x;
    for (int b = tid; b < NBUCKET; b += 256) h[b] = 0;
    __syncthreads();
    size_t base = (size_t)blk * EPB;
    if (flag[0]) {
        const unsigned long long* cols = (const unsigned long long*)ei + N_EDGES;
        for (int i = tid; i < EPB; i += 256)
            atomicAdd(&h[((uint32_t)cols[base + i]) >> 10], 1);
    } else {
        const int* cols = (const int*)ei + N_EDGES;
        for (int i = tid; i < EPB; i += 256)
            atomicAdd(&h[((uint32_t)cols[base + i]) >> 10], 1);
    }
    __syncthreads();
    for (int b = tid; b < NBUCKET; b += 256) bhist[b * NBLK + blk] = h[b];
}

// ---------------- exclusive scan of bhist[512K] -> bh_scan ------------------
__global__ void scan_local_kernel(const int* __restrict__ in, int* __restrict__ out,
                                  int* __restrict__ bsum) {
    __shared__ int sh[256];
    int b = blockIdx.x, t = threadIdx.x;
    int idx = b * 1024 + t * 4;
    int a0 = in[idx], a1 = in[idx + 1], a2 = in[idx + 2], a3 = in[idx + 3];
    int s = a0 + a1 + a2 + a3;
    sh[t] = s;
    __syncthreads();
    for (int off = 1; off < 256; off <<= 1) {
        int v = (t >= off) ? sh[t - off] : 0;
        __syncthreads();
        sh[t] += v;
        __syncthreads();
    }
    int eb = sh[t] - s;
    out[idx]     = eb;
    out[idx + 1] = eb + a0;
    out[idx + 2] = eb + a0 + a1;
    out[idx + 3] = eb + a0 + a1 + a2;
    if (t == 255) bsum[b] = sh[255];
}

// scan 512 block sums (single block, 2 per thread)
__global__ void scan_bsums512_kernel(const int* __restrict__ bsum, int* __restrict__ bbase) {
    __shared__ int sh[256];
    int t = threadIdx.x;
    int a0 = bsum[2 * t], a1 = bsum[2 * t + 1];
    int s = a0 + a1;
    sh[t] = s;
    __syncthreads();
    for (int off = 1; off < 256; off <<= 1) {
        int v = (t >= off) ? sh[t - off] : 0;
        __syncthreads();
        sh[t] += v;
        __syncthreads();
    }
    int eb = sh[t] - s;
    bbase[2 * t]     = eb;
    bbase[2 * t + 1] = eb + a0;
    if (t == 255) bbase[512] = sh[255];
}

__global__ void scan_add512_kernel(int* __restrict__ out, const int* __restrict__ bbase) {
    int i = blockIdx.x * blockDim.x + threadIdx.x;
    out[i] += bbase[i >> 10];
    if (i == 0) out[NBUCKET * NBLK] = bbase[512];  // sentinel = N_EDGES
}

// ---------------------------------------------------------------------------
// Phase A3: scatter edges into bucket regions as packed u32 (row<<10 | col_lo).
// Position = bh_scan[bucket*NBLK + blk] + LDS rank. No global atomics.
__global__ void scatter_pack_kernel(const void* __restrict__ ei, const int* __restrict__ flag,
                                    const int* __restrict__ bh_scan,
                                    uint32_t* __restrict__ packed) {
    __shared__ int cnt[NBUCKET];
    int blk = blockIdx.x, tid = threadIdx.x;
    for (int b = tid; b < NBUCKET; b += 256) cnt[b] = bh_scan[b * NBLK + blk];
    __syncthreads();
    size_t base = (size_t)blk * EPB;
    if (flag[0]) {
        const unsigned long long* rows = (const unsigned long long*)ei;
        const unsigned long long* cols = rows + N_EDGES;
        for (int i = tid; i < EPB; i += 256) {
            uint32_t r = (uint32_t)rows[base + i];
            uint32_t c = (uint32_t)cols[base + i];
            int pos = atomicAdd(&cnt[c >> 10], 1);
            packed[pos] = (r << 10) | (c & 1023u);
        }
    } else {
        const uint32_t* rows = (const uint32_t*)ei;
        const uint32_t* cols = rows + N_EDGES;
        for (int i = tid; i < EPB; i += 256) {
            uint32_t r = rows[base + i];
            uint32_t c = cols[base + i];
            int pos = atomicAdd(&cnt[c >> 10], 1);
            packed[pos] = (r << 10) | (c & 1023u);
        }
    }
}

// ---------------------------------------------------------------------------
// Per-bucket degree + dinv (LDS histogram; no global atomics).
__global__ void degdinv_kernel(const uint32_t* __restrict__ packed,
                               const int* __restrict__ bh_scan,
                               float* __restrict__ dinv) {
    __shared__ int h[CPB];
    int b = blockIdx.x, tid = threadIdx.x;
    for (int l = tid; l < CPB; l += 256) h[l] = 0;
    __syncthreads();
    int s = bh_scan[b * NBLK];
    int e = bh_scan[(b + 1) * NBLK];  // sentinel valid for b = NBUCKET-1
    for (int i = s + tid; i < e; i += 256)
        atomicAdd(&h[packed[i] & 1023u], 1);
    __syncthreads();
    for (int l = tid; l < CPB; l += 256) {
        int v = b * CPB + l;
        dinv[v] = (float)(1.0 / sqrt((double)(h[l] + 1)));  // +1 self loop
    }
}

// z0 = dinv * x
__global__ void prep_first_kernel(const float* __restrict__ x, const float* __restrict__ dinv,
                                  float* __restrict__ z) {
    int v = blockIdx.x * blockDim.x + threadIdx.x;
    z[v] = dinv[v] * x[v];
}

// ---------------------------------------------------------------------------
// Bucketed push hop: block b accumulates z[row] into LDS facc[col_lo], then
// t[v] = z[v] + facc;  out = mode ? d^2*t (next z) : d*t (final x).
__global__ void hop_kernel(const uint32_t* __restrict__ packed,
                           const int* __restrict__ bh_scan,
                           const float* __restrict__ z, const float* __restrict__ dinv,
                           float* __restrict__ out, int mode) {
    __shared__ float facc[CPB];
    int b = blockIdx.x, tid = threadIdx.x;
    for (int l = tid; l < CPB; l += 256) facc[l] = 0.0f;
    __syncthreads();
    int s = bh_scan[b * NBLK];
    int e = bh_scan[(b + 1) * NBLK];
    for (int i = s + tid; i < e; i += 256) {
        uint32_t p = packed[i];
        atomicAdd(&facc[p & 1023u], z[p >> 10]);
    }
    __syncthreads();
    for (int l = tid; l < CPB; l += 256) {
        int v = b * CPB + l;
        float t = z[v] + facc[l];
        float d = dinv[v];
        out[v] = mode ? d * d * t : d * t;
    }
}

// out[g] = W * mean_{chunk g}(xf) + b
__global__ void pool_kernel(const float* __restrict__ xf,
                            const float* __restrict__ W, const float* __restrict__ b,
                            float* __restrict__ out) {
    __shared__ double sdata[256];
    int g = blockIdx.x;
    int base = g * CHUNK;
    double s = 0.0;
    for (int i = threadIdx.x; i < CHUNK; i += 256) s += (double)xf[base + i];
    sdata[threadIdx.x] = s;
    __syncthreads();
    for (int off = 128; off > 0; off >>= 1) {
        if (threadIdx.x < off) sdata[threadIdx.x] += sdata[threadIdx.x + off];
        __syncthreads();
    }
    if (threadIdx.x == 0)
        out[g] = (float)((double)W[0] * (sdata[0] / (double)CHUNK) + (double)b[0]);
}

// ---------------- fallback (push, atomics) for small ws ---------------------
__device__ __forceinline__ int load_idx(const void* ei, int is64, size_t pos) {
    if (is64) return (int)((const unsigned long long*)ei)[pos];
    return ((const int*)ei)[pos];
}

__global__ void zero_int_kernel(int* __restrict__ p) {
    int i = blockIdx.x * blockDim.x + threadIdx.x;
    p[i] = 0;
}

__global__ void count_kernel(const void* __restrict__ ei, const int* __restrict__ flag,
                             int* __restrict__ deg) {
    int e = blockIdx.x * blockDim.x + threadIdx.x;
    int c = load_idx(ei, flag[0], (size_t)N_EDGES + (size_t)e);
    atomicAdd(&deg[c], 1);
}

__global__ void dinv_kernel(const int* __restrict__ deg, float* __restrict__ dinv) {
    int v = blockIdx.x * blockDim.x + threadIdx.x;
    dinv[v] = (float)(1.0 / sqrt((double)(deg[v] + 1)));
}

__global__ void prep_first2_kernel(const float* __restrict__ x, const float* __restrict__ dinv,
                                   float* __restrict__ z, float* __restrict__ acc) {
    int v = blockIdx.x * blockDim.x + threadIdx.x;
    float t = dinv[v] * x[v];
    z[v] = t;
    acc[v] = t;
}

__global__ void prep_mid_kernel(const float* __restrict__ dinv,
                                float* __restrict__ z, float* __restrict__ acc) {
    int v = blockIdx.x * blockDim.x + threadIdx.x;
    float d = dinv[v];
    float t = d * d * acc[v];
    z[v] = t;
    acc[v] = t;
}

__global__ void push_kernel(const void* __restrict__ ei, const int* __restrict__ flag,
                            const float* __restrict__ z, float* __restrict__ acc) {
    int e = blockIdx.x * blockDim.x + threadIdx.x;
    int is64 = flag[0];
    int r, c;
    if (is64) {
        const unsigned long long* p = (const unsigned long long*)ei;
        r = (int)p[e];
        c = (int)p[(size_t)N_EDGES + (size_t)e];
    } else {
        const int* p = (const int*)ei;
        r = p[e];
        c = p[(size_t)N_EDGES + (size_t)e];
    }
    __hip_atomic_fetch_add(&acc[c], z[r], __ATOMIC_RELAXED, __HIP_MEMORY_SCOPE_AGENT);
}

__global__ void final_scale_kernel(const float* __restrict__ dinv,
                                   const float* __restrict__ acc, float* __restrict__ xf) {
    int v = blockIdx.x * blockDim.x + threadIdx.x;
    xf[v] = dinv[v] * acc[v];
}

extern "C" void kernel_launch(void* const* d_in, const int* in_sizes, int n_in,
                              void* d_out, int out_size, void* d_ws, size_t ws_size,
                              hipStream_t stream) {
    const float* x = (const float*)d_in[0];
    const void*  ei = d_in[1];
    const float* W = (const float*)d_in[2];
    const float* b = (const float*)d_in[3];
    float* out = (float*)d_out;

    char* ws = (char*)d_ws;
    const size_t MB4 = 4ull << 20;
    size_t off_flag   = 0;                               // 256 B
    size_t off_bhist  = 256;                             // 512K ints = 2 MB
    size_t off_scan   = off_bhist + (NBUCKET * NBLK * 4);            // 512K+1 ints
    size_t off_bsum   = off_scan + (NBUCKET * NBLK * 4 + 256);       // 512 ints
    size_t off_bbase  = off_bsum + 2048;                 // 513 ints
    size_t off_dinv   = off_bbase + 2304;                // 4 MB
    size_t off_za     = off_dinv + MB4;                  // 4 MB
    size_t off_zb     = off_za + MB4;                    // 4 MB
    size_t off_packed = off_zb + MB4;                    // 64 MB
    size_t needed     = off_packed + (size_t)N_EDGES * 4;

    const int TB = 256;

    if (ws_size >= needed) {
        int*      flag   = (int*)(ws + off_flag);
        int*      bhist  = (int*)(ws + off_bhist);
        int*      bscan  = (int*)(ws + off_scan);
        int*      bsum   = (int*)(ws + off_bsum);
        int*      bbase  = (int*)(ws + off_bbase);
        float*    dinv   = (float*)(ws + off_dinv);
        float*    za     = (float*)(ws + off_za);
        float*    zb     = (float*)(ws + off_zb);
        uint32_t* packed = (uint32_t*)(ws + off_packed);

        detect_kernel<<<1, TB, 0, stream>>>((const uint32_t*)ei, flag);
        bucket_hist_kernel<<<NBLK, TB, 0, stream>>>(ei, flag, bhist);

        scan_local_kernel<<<NBUCKET * NBLK / 1024, TB, 0, stream>>>(bhist, bscan, bsum);
        scan_bsums512_kernel<<<1, TB, 0, stream>>>(bsum, bbase);
        scan_add512_kernel<<<NBUCKET * NBLK / TB, TB, 0, stream>>>(bscan, bbase);

        scatter_pack_kernel<<<NBLK, TB, 0, stream>>>(ei, flag, bscan, packed);
        degdinv_kernel<<<NBUCKET, TB, 0, stream>>>(packed, bscan, dinv);

        prep_first_kernel<<<N_NODES / TB, TB, 0, stream>>>(x, dinv, za);
        hop_kernel<<<NBUCKET, TB, 0, stream>>>(packed, bscan, za, dinv, zb, 1);
        hop_kernel<<<NBUCKET, TB, 0, stream>>>(packed, bscan, zb, dinv, za, 1);
        hop_kernel<<<NBUCKET, TB, 0, stream>>>(packed, bscan, za, dinv, zb, 1);
        hop_kernel<<<NBUCKET, TB, 0, stream>>>(packed, bscan, zb, dinv, za, 0);

        pool_kernel<<<N_GRAPHS, TB, 0, stream>>>(za, W, b, out);
    } else {
        // Fallback: push-based with atomics.
        int*   flag = (int*)ws;
        float* dinv = (float*)(ws + 256);
        float* za   = (float*)(ws + 256 + MB4);
        float* zb   = (float*)(ws + 256 + 2 * MB4);
        int*   deg  = (int*)(ws + 256 + 3 * MB4);

        detect_kernel<<<1, TB, 0, stream>>>((const uint32_t*)ei, flag);
        zero_int_kernel<<<N_NODES / TB, TB, 0, stream>>>(deg);
        count_kernel<<<N_EDGES / TB, TB, 0, stream>>>(ei, flag, deg);
        dinv_kernel<<<N_NODES / TB, TB, 0, stream>>>(deg, dinv);

        prep_first2_kernel<<<N_NODES / TB, TB, 0, stream>>>(x, dinv, za, zb);
        push_kernel<<<N_EDGES / TB, TB, 0, stream>>>(ei, flag, za, zb);
        for (int h = 1; h < K_HOPS; ++h) {
            prep_mid_kernel<<<N_NODES / TB, TB, 0, stream>>>(dinv, za, zb);
            push_kernel<<<N_EDGES / TB, TB, 0, stream>>>(ei, flag, za, zb);
        }
        final_scale_kernel<<<N_NODES / TB, TB, 0, stream>>>(dinv, zb, za);
        pool_kernel<<<N_GRAPHS, TB, 0, stream>>>(za, W, b, out);
    }
}

// Round 4
// 849.891 us; speedup vs baseline: 4.7942x; 1.2203x over previous
//
#include <hip/hip_runtime.h>
#include <stdint.h>

#define N_NODES  (1u << 20)      // 1048576
#define N_EDGES  (1u << 24)      // 16777216
#define N_GRAPHS 64
#define CHUNK    (N_NODES / N_GRAPHS)  // 16384
#define K_HOPS   4

#define NBUCKET  1024            // column buckets
#define CPB      1024            // cols per bucket
#define CAP      18432           // slots per bucket region (λ=16384, +16σ)
#define NBLK_S   512             // scatter blocks
#define TB_S     512             // scatter threads
#define EPB_S    (N_EDGES / NBLK_S)  // 32768
#define STAGE_CAP 16

// ---------------------------------------------------------------------------
// Edge dtype detection: int64 little-endian with values < 2^20 has all-zero
// odd u32 words; int32 has random indices there. flag[0]=1 -> int64.
__global__ void detect_kernel(const uint32_t* __restrict__ ei, int* __restrict__ flag) {
    __shared__ int any_nz;
    if (threadIdx.x == 0) any_nz = 0;
    __syncthreads();
    int nz = 0;
    for (int i = threadIdx.x; i < 32768; i += blockDim.x)
        nz |= (ei[2 * i + 1] != 0u);
    if (nz) atomicOr(&any_nz, 1);
    __syncthreads();
    if (threadIdx.x == 0) flag[0] = any_nz ? 0 : 1;
}

__global__ void zero_int_kernel(int* __restrict__ p) {
    int i = blockIdx.x * blockDim.x + threadIdx.x;
    p[i] = 0;
}

// ---------------------------------------------------------------------------
// Single-pass scatter: LDS-stage 16 entries/bucket, flush multiples of 8
// entries (32B-aligned: cursor positions only ever advance by multiples of 8
// except rare overflow/drain) via one global atomicAdd per flush.
__global__ void scatter_atomic_kernel(const void* __restrict__ ei, const int* __restrict__ flag,
                                      int* __restrict__ cursor, uint32_t* __restrict__ packed) {
    __shared__ uint32_t stage[NBUCKET * STAGE_CAP];  // 64 KB
    __shared__ int cnt[NBUCKET];                     // 4 KB
    int blk = blockIdx.x, tid = threadIdx.x;
    for (int b = tid; b < NBUCKET; b += TB_S) cnt[b] = 0;
    __syncthreads();
    size_t base = (size_t)blk * EPB_S;
    int is64 = flag[0];

    for (int it = 0; it < EPB_S / (TB_S * 2); ++it) {
        size_t i = base + (size_t)it * (TB_S * 2) + (size_t)tid * 2;
        uint32_t r0, r1, c0, c1;
        if (is64) {
            ulonglong2 rr = *(const ulonglong2*)((const unsigned long long*)ei + i);
            ulonglong2 cc = *(const ulonglong2*)((const unsigned long long*)ei + N_EDGES + i);
            r0 = (uint32_t)rr.x; r1 = (uint32_t)rr.y;
            c0 = (uint32_t)cc.x; c1 = (uint32_t)cc.y;
        } else {
            uint2 rr = *(const uint2*)((const uint32_t*)ei + i);
            uint2 cc = *(const uint2*)((const uint32_t*)ei + N_EDGES + i);
            r0 = rr.x; r1 = rr.y; c0 = cc.x; c1 = cc.y;
        }
        {
            int b = c0 >> 10; uint32_t val = (r0 << 10) | (c0 & 1023u);
            int s = atomicAdd(&cnt[b], 1);
            if (s < STAGE_CAP) stage[b * STAGE_CAP + s] = val;
            else { int pos = atomicAdd(&cursor[b], 1); if (pos < CAP) packed[(size_t)b * CAP + pos] = val; }
        }
        {
            int b = c1 >> 10; uint32_t val = (r1 << 10) | (c1 & 1023u);
            int s = atomicAdd(&cnt[b], 1);
            if (s < STAGE_CAP) stage[b * STAGE_CAP + s] = val;
            else { int pos = atomicAdd(&cursor[b], 1); if (pos < CAP) packed[(size_t)b * CAP + pos] = val; }
        }
        __syncthreads();
        // flush phase: each thread owns NBUCKET/TB_S = 2 buckets
        for (int k = 0; k < NBUCKET / TB_S; ++k) {
            int b = tid + k * TB_S;
            int c = cnt[b];
            int cs = c < STAGE_CAP ? c : STAGE_CAP;
            int f = cs & ~7;
            if (f > 0) {
                int pos = atomicAdd(&cursor[b], f);
                if (pos + f <= CAP) {
                    uint32_t* dst = packed + (size_t)b * CAP + pos;
                    const uint32_t* src = &stage[b * STAGE_CAP];
                    for (int j = 0; j < f; j += 4)
                        *(uint4*)(dst + j) = *(const uint4*)(src + j);
                }
                int rem = cs - f;
                for (int j = 0; j < rem; ++j)
                    stage[b * STAGE_CAP + j] = stage[b * STAGE_CAP + f + j];
                cnt[b] = rem;
            } else {
                cnt[b] = cs;
            }
        }
        __syncthreads();
    }
    // final drain (cnt <= 7 per bucket)
    for (int k = 0; k < NBUCKET / TB_S; ++k) {
        int b = tid + k * TB_S;
        int c = cnt[b];
        if (c > 0) {
            int pos = atomicAdd(&cursor[b], c);
            for (int j = 0; j < c; ++j)
                if (pos + j < CAP) packed[(size_t)b * CAP + pos + j] = stage[b * STAGE_CAP + j];
        }
    }
}

// ---------------------------------------------------------------------------
// Per-bucket degree -> dinv, fused with z0 = dinv * x.
__global__ void degdinv_kernel(const uint32_t* __restrict__ packed, const int* __restrict__ cursor,
                               const float* __restrict__ x,
                               float* __restrict__ dinv, float* __restrict__ z) {
    __shared__ int h[CPB];
    int b = blockIdx.x, tid = threadIdx.x;
    for (int l = tid; l < CPB; l += 512) h[l] = 0;
    __syncthreads();
    int cnt = cursor[b]; if (cnt > CAP) cnt = CAP;
    const uint32_t* seg = packed + (size_t)b * CAP;
    int nv = cnt >> 2;
    for (int g = tid; g < nv; g += 512) {
        uint4 v = *(const uint4*)(seg + g * 4);
        atomicAdd(&h[v.x & 1023u], 1);
        atomicAdd(&h[v.y & 1023u], 1);
        atomicAdd(&h[v.z & 1023u], 1);
        atomicAdd(&h[v.w & 1023u], 1);
    }
    int t = nv * 4 + tid;
    if (t < cnt) atomicAdd(&h[seg[t] & 1023u], 1);
    __syncthreads();
    for (int l = tid; l < CPB; l += 512) {
        int v = b * CPB + l;
        float d = (float)(1.0 / sqrt((double)(h[l] + 1)));  // +1 self loop
        dinv[v] = d;
        z[v] = d * x[v];
    }
}

// ---------------------------------------------------------------------------
// Bucketed hop: LDS accumulate z[row] per local col, then
// t[v] = z[v] + facc;  out = mode ? d^2*t (next z) : d*t (final x).
__global__ void hop_kernel(const uint32_t* __restrict__ packed, const int* __restrict__ cursor,
                           const float* __restrict__ z, const float* __restrict__ dinv,
                           float* __restrict__ out, int mode) {
    __shared__ float facc[CPB];
    int b = blockIdx.x, tid = threadIdx.x;
    for (int l = tid; l < CPB; l += 512) facc[l] = 0.0f;
    __syncthreads();
    int cnt = cursor[b]; if (cnt > CAP) cnt = CAP;
    const uint32_t* seg = packed + (size_t)b * CAP;
    int nv = cnt >> 2;
    for (int g = tid; g < nv; g += 512) {
        uint4 v = *(const uint4*)(seg + g * 4);
        float z0 = z[v.x >> 10];
        float z1 = z[v.y >> 10];
        float z2 = z[v.z >> 10];
        float z3 = z[v.w >> 10];
        atomicAdd(&facc[v.x & 1023u], z0);
        atomicAdd(&facc[v.y & 1023u], z1);
        atomicAdd(&facc[v.z & 1023u], z2);
        atomicAdd(&facc[v.w & 1023u], z3);
    }
    int t = nv * 4 + tid;
    if (t < cnt) { uint32_t p = seg[t]; atomicAdd(&facc[p & 1023u], z[p >> 10]); }
    __syncthreads();
    for (int l = tid; l < CPB; l += 512) {
        int v = b * CPB + l;
        float tt = z[v] + facc[l];
        float d = dinv[v];
        out[v] = mode ? d * d * tt : d * tt;
    }
}

// out[g] = W * mean_{chunk g}(xf) + b
__global__ void pool_kernel(const float* __restrict__ xf,
                            const float* __restrict__ W, const float* __restrict__ b,
                            float* __restrict__ out) {
    __shared__ double sdata[256];
    int g = blockIdx.x;
    int base = g * CHUNK;
    double s = 0.0;
    for (int i = threadIdx.x; i < CHUNK; i += 256) s += (double)xf[base + i];
    sdata[threadIdx.x] = s;
    __syncthreads();
    for (int off = 128; off > 0; off >>= 1) {
        if (threadIdx.x < off) sdata[threadIdx.x] += sdata[threadIdx.x + off];
        __syncthreads();
    }
    if (threadIdx.x == 0)
        out[g] = (float)((double)W[0] * (sdata[0] / (double)CHUNK) + (double)b[0]);
}

// ---------------- fallback (push, atomics) for small ws ---------------------
__device__ __forceinline__ int load_idx(const void* ei, int is64, size_t pos) {
    if (is64) return (int)((const unsigned long long*)ei)[pos];
    return ((const int*)ei)[pos];
}

__global__ void count_kernel(const void* __restrict__ ei, const int* __restrict__ flag,
                             int* __restrict__ deg) {
    int e = blockIdx.x * blockDim.x + threadIdx.x;
    int c = load_idx(ei, flag[0], (size_t)N_EDGES + (size_t)e);
    atomicAdd(&deg[c], 1);
}

__global__ void dinv_kernel(const int* __restrict__ deg, float* __restrict__ dinv) {
    int v = blockIdx.x * blockDim.x + threadIdx.x;
    dinv[v] = (float)(1.0 / sqrt((double)(deg[v] + 1)));
}

__global__ void prep_first2_kernel(const float* __restrict__ x, const float* __restrict__ dinv,
                                   float* __restrict__ z, float* __restrict__ acc) {
    int v = blockIdx.x * blockDim.x + threadIdx.x;
    float t = dinv[v] * x[v];
    z[v] = t;
    acc[v] = t;
}

__global__ void prep_mid_kernel(const float* __restrict__ dinv,
                                float* __restrict__ z, float* __restrict__ acc) {
    int v = blockIdx.x * blockDim.x + threadIdx.x;
    float d = dinv[v];
    float t = d * d * acc[v];
    z[v] = t;
    acc[v] = t;
}

__global__ void push_kernel(const void* __restrict__ ei, const int* __restrict__ flag,
                            const float* __restrict__ z, float* __restrict__ acc) {
    int e = blockIdx.x * blockDim.x + threadIdx.x;
    int is64 = flag[0];
    int r, c;
    if (is64) {
        const unsigned long long* p = (const unsigned long long*)ei;
        r = (int)p[e];
        c = (int)p[(size_t)N_EDGES + (size_t)e];
    } else {
        const int* p = (const int*)ei;
        r = p[e];
        c = p[(size_t)N_EDGES + (size_t)e];
    }
    __hip_atomic_fetch_add(&acc[c], z[r], __ATOMIC_RELAXED, __HIP_MEMORY_SCOPE_AGENT);
}

__global__ void final_scale_kernel(const float* __restrict__ dinv,
                                   const float* __restrict__ acc, float* __restrict__ xf) {
    int v = blockIdx.x * blockDim.x + threadIdx.x;
    xf[v] = dinv[v] * acc[v];
}

extern "C" void kernel_launch(void* const* d_in, const int* in_sizes, int n_in,
                              void* d_out, int out_size, void* d_ws, size_t ws_size,
                              hipStream_t stream) {
    const float* x = (const float*)d_in[0];
    const void*  ei = d_in[1];
    const float* W = (const float*)d_in[2];
    const float* b = (const float*)d_in[3];
    float* out = (float*)d_out;

    char* ws = (char*)d_ws;
    const size_t MB4 = 4ull << 20;
    size_t off_flag   = 0;                                // 256 B
    size_t off_cursor = 256;                              // 4 KB
    size_t off_dinv   = off_cursor + NBUCKET * 4;         // 4 MB
    size_t off_za     = off_dinv + MB4;                   // 4 MB
    size_t off_zb     = off_za + MB4;                     // 4 MB
    size_t off_packed = off_zb + MB4;                     // 72 MB
    size_t needed     = off_packed + (size_t)NBUCKET * CAP * 4;

    const int TB = 256;

    if (ws_size >= needed) {
        int*      flag   = (int*)(ws + off_flag);
        int*      cursor = (int*)(ws + off_cursor);
        float*    dinv   = (float*)(ws + off_dinv);
        float*    za     = (float*)(ws + off_za);
        float*    zb     = (float*)(ws + off_zb);
        uint32_t* packed = (uint32_t*)(ws + off_packed);

        detect_kernel<<<1, TB, 0, stream>>>((const uint32_t*)ei, flag);
        zero_int_kernel<<<NBUCKET / TB, TB, 0, stream>>>(cursor);
        scatter_atomic_kernel<<<NBLK_S, TB_S, 0, stream>>>(ei, flag, cursor, packed);
        degdinv_kernel<<<NBUCKET, 512, 0, stream>>>(packed, cursor, x, dinv, za);

        hop_kernel<<<NBUCKET, 512, 0, stream>>>(packed, cursor, za, dinv, zb, 1);
        hop_kernel<<<NBUCKET, 512, 0, stream>>>(packed, cursor, zb, dinv, za, 1);
        hop_kernel<<<NBUCKET, 512, 0, stream>>>(packed, cursor, za, dinv, zb, 1);
        hop_kernel<<<NBUCKET, 512, 0, stream>>>(packed, cursor, zb, dinv, za, 0);

        pool_kernel<<<N_GRAPHS, TB, 0, stream>>>(za, W, b, out);
    } else {
        // Fallback: push-based with atomics.
        int*   flag = (int*)ws;
        float* dinv = (float*)(ws + 256);
        float* za   = (float*)(ws + 256 + MB4);
        float* zb   = (float*)(ws + 256 + 2 * MB4);
        int*   deg  = (int*)(ws + 256 + 3 * MB4);

        detect_kernel<<<1, TB, 0, stream>>>((const uint32_t*)ei, flag);
        zero_int_kernel<<<N_NODES / TB, TB, 0, stream>>>(deg);
        count_kernel<<<N_EDGES / TB, TB, 0, stream>>>(ei, flag, deg);
        dinv_kernel<<<N_NODES / TB, TB, 0, stream>>>(deg, dinv);

        prep_first2_kernel<<<N_NODES / TB, TB, 0, stream>>>(x, dinv, za, zb);
        push_kernel<<<N_EDGES / TB, TB, 0, stream>>>(ei, flag, za, zb);
        for (int h = 1; h < K_HOPS; ++h) {
            prep_mid_kernel<<<N_NODES / TB, TB, 0, stream>>>(dinv, za, zb);
            push_kernel<<<N_EDGES / TB, TB, 0, stream>>>(ei, flag, za, zb);
        }
        final_scale_kernel<<<N_NODES / TB, TB, 0, stream>>>(dinv, zb, za);
        pool_kernel<<<N_GRAPHS, TB, 0, stream>>>(za, W, b, out);
    }
}

// Round 5
// 656.928 us; speedup vs baseline: 6.2024x; 1.2937x over previous
//
#include <hip/hip_runtime.h>
#include <stdint.h>

#define N_NODES  (1u << 20)      // 1048576
#define N_EDGES  (1u << 24)      // 16777216
#define N_GRAPHS 64
#define CHUNK    (N_NODES / N_GRAPHS)  // 16384
#define K_HOPS   4

#define NBUCKET  1024            // column buckets
#define CPB      1024            // cols per bucket
#define CAP      18432           // slots per bucket region (λ=16384, +16σ)

#define NBLK_SS  512             // scatter-sort blocks
#define TB_SS    1024            // scatter-sort threads
#define EPT      32              // edges per thread
#define EPB_SS   (TB_SS * EPT)   // 32768 edges per block

// ---------------------------------------------------------------------------
// Edge dtype detection: int64 little-endian with values < 2^20 has all-zero
// odd u32 words; int32 has random indices there. flag[0]=1 -> int64.
__global__ void detect_kernel(const uint32_t* __restrict__ ei, int* __restrict__ flag) {
    __shared__ int any_nz;
    if (threadIdx.x == 0) any_nz = 0;
    __syncthreads();
    int nz = 0;
    for (int i = threadIdx.x; i < 32768; i += blockDim.x)
        nz |= (ei[2 * i + 1] != 0u);
    if (nz) atomicOr(&any_nz, 1);
    __syncthreads();
    if (threadIdx.x == 0) flag[0] = any_nz ? 0 : 1;
}

__global__ void zero_int_kernel(int* __restrict__ p) {
    int i = blockIdx.x * blockDim.x + threadIdx.x;
    p[i] = 0;
}

// ---------------------------------------------------------------------------
// Per-block LDS counting sort by bucket, then coalesced run write-out.
// Phase A: cols -> registers + LDS bucket histogram.
// Phase B: wave-0 exclusive scan; per-bucket global cursor reserve.
// Phase C: rows -> LDS-sorted packed entries (pos via LDS atomic on offsets).
// Phase D: each wave copies 64 bucket runs to global (contiguous, coalesced).
__global__ __launch_bounds__(TB_SS, 4)
void scatter_sort_kernel(const void* __restrict__ ei, const int* __restrict__ flag,
                         int* __restrict__ cursor, uint32_t* __restrict__ packed) {
    __shared__ uint32_t sorted[EPB_SS];   // 128 KB
    __shared__ int h[NBUCKET];            // 4 KB
    __shared__ int o[NBUCKET];            // 4 KB (scan, then bumped by scatter)
    __shared__ int ostart[NBUCKET];       // 4 KB (stable run starts)
    __shared__ int gbase[NBUCKET];        // 4 KB
    int blk = blockIdx.x, tid = threadIdx.x;
    h[tid] = 0;
    __syncthreads();
    size_t base = (size_t)blk * EPB_SS;
    int is64 = flag[0];
    uint32_t c_[EPT];

    // Phase A: load cols, histogram buckets.
    if (is64) {
        const unsigned long long* cp = (const unsigned long long*)ei + N_EDGES + base;
        #pragma unroll
        for (int it = 0; it < EPT / 4; ++it) {
            size_t i = (size_t)it * (TB_SS * 4) + (size_t)tid * 4;
            ulonglong2 a = *(const ulonglong2*)(cp + i);
            ulonglong2 b2 = *(const ulonglong2*)(cp + i + 2);
            c_[it * 4 + 0] = (uint32_t)a.x;  c_[it * 4 + 1] = (uint32_t)a.y;
            c_[it * 4 + 2] = (uint32_t)b2.x; c_[it * 4 + 3] = (uint32_t)b2.y;
            atomicAdd(&h[c_[it * 4 + 0] >> 10], 1);
            atomicAdd(&h[c_[it * 4 + 1] >> 10], 1);
            atomicAdd(&h[c_[it * 4 + 2] >> 10], 1);
            atomicAdd(&h[c_[it * 4 + 3] >> 10], 1);
        }
    } else {
        const uint32_t* cp = (const uint32_t*)ei + N_EDGES + base;
        #pragma unroll
        for (int it = 0; it < EPT / 4; ++it) {
            size_t i = (size_t)it * (TB_SS * 4) + (size_t)tid * 4;
            uint4 a = *(const uint4*)(cp + i);
            c_[it * 4 + 0] = a.x; c_[it * 4 + 1] = a.y;
            c_[it * 4 + 2] = a.z; c_[it * 4 + 3] = a.w;
            atomicAdd(&h[a.x >> 10], 1);
            atomicAdd(&h[a.y >> 10], 1);
            atomicAdd(&h[a.z >> 10], 1);
            atomicAdd(&h[a.w >> 10], 1);
        }
    }
    __syncthreads();

    // Phase B: wave 0 exclusive-scans h[1024] -> o/ostart.
    if (tid < 64) {
        int b16 = tid * 16;
        int s = 0;
        #pragma unroll
        for (int j = 0; j < 16; ++j) s += h[b16 + j];
        int v = s;
        #pragma unroll
        for (int off = 1; off < 64; off <<= 1) {
            int up = __shfl_up(v, off, 64);
            if (tid >= off) v += up;
        }
        int run = v - s;  // exclusive
        #pragma unroll
        for (int j = 0; j < 16; ++j) {
            o[b16 + j] = run;
            ostart[b16 + j] = run;
            run += h[b16 + j];
        }
    }
    __syncthreads();

    // Per-bucket global reserve (1 atomic per bucket per block).
    gbase[tid] = atomicAdd(&cursor[tid], h[tid]);

    // Phase C: load rows, scatter packed entries into LDS sorted buffer.
    if (is64) {
        const unsigned long long* rp = (const unsigned long long*)ei + base;
        #pragma unroll
        for (int it = 0; it < EPT / 4; ++it) {
            size_t i = (size_t)it * (TB_SS * 4) + (size_t)tid * 4;
            ulonglong2 a = *(const ulonglong2*)(rp + i);
            ulonglong2 b2 = *(const ulonglong2*)(rp + i + 2);
            uint32_t r0 = (uint32_t)a.x, r1 = (uint32_t)a.y;
            uint32_t r2 = (uint32_t)b2.x, r3 = (uint32_t)b2.y;
            { uint32_t c = c_[it * 4 + 0]; int pos = atomicAdd(&o[c >> 10], 1); sorted[pos] = (r0 << 10) | (c & 1023u); }
            { uint32_t c = c_[it * 4 + 1]; int pos = atomicAdd(&o[c >> 10], 1); sorted[pos] = (r1 << 10) | (c & 1023u); }
            { uint32_t c = c_[it * 4 + 2]; int pos = atomicAdd(&o[c >> 10], 1); sorted[pos] = (r2 << 10) | (c & 1023u); }
            { uint32_t c = c_[it * 4 + 3]; int pos = atomicAdd(&o[c >> 10], 1); sorted[pos] = (r3 << 10) | (c & 1023u); }
        }
    } else {
        const uint32_t* rp = (const uint32_t*)ei + base;
        #pragma unroll
        for (int it = 0; it < EPT / 4; ++it) {
            size_t i = (size_t)it * (TB_SS * 4) + (size_t)tid * 4;
            uint4 a = *(const uint4*)(rp + i);
            { uint32_t c = c_[it * 4 + 0]; int pos = atomicAdd(&o[c >> 10], 1); sorted[pos] = (a.x << 10) | (c & 1023u); }
            { uint32_t c = c_[it * 4 + 1]; int pos = atomicAdd(&o[c >> 10], 1); sorted[pos] = (a.y << 10) | (c & 1023u); }
            { uint32_t c = c_[it * 4 + 2]; int pos = atomicAdd(&o[c >> 10], 1); sorted[pos] = (a.z << 10) | (c & 1023u); }
            { uint32_t c = c_[it * 4 + 3]; int pos = atomicAdd(&o[c >> 10], 1); sorted[pos] = (a.w << 10) | (c & 1023u); }
        }
    }
    __syncthreads();

    // Phase D: write-out. Wave w copies buckets [w*64, w*64+64); runs contiguous.
    int wave = tid >> 6, lane = tid & 63;
    for (int k = 0; k < NBUCKET / 16; ++k) {
        int b = wave * (NBUCKET / 16) + k;
        int st = ostart[b];
        int len = o[b] - st;
        int gb = gbase[b];
        uint32_t* dst = packed + (size_t)b * CAP + gb;
        for (int j = lane; j < len; j += 64)
            if (gb + j < CAP) dst[j] = sorted[st + j];
    }
}

// ---------------------------------------------------------------------------
// Per-bucket degree -> dinv, fused with z0 = dinv * x.
__global__ void degdinv_kernel(const uint32_t* __restrict__ packed, const int* __restrict__ cursor,
                               const float* __restrict__ x,
                               float* __restrict__ dinv, float* __restrict__ z) {
    __shared__ int h[CPB];
    int b = blockIdx.x, tid = threadIdx.x;
    for (int l = tid; l < CPB; l += 512) h[l] = 0;
    __syncthreads();
    int cnt = cursor[b]; if (cnt > CAP) cnt = CAP;
    const uint32_t* seg = packed + (size_t)b * CAP;
    int nv = cnt >> 2;
    for (int g = tid; g < nv; g += 512) {
        uint4 v = *(const uint4*)(seg + g * 4);
        atomicAdd(&h[v.x & 1023u], 1);
        atomicAdd(&h[v.y & 1023u], 1);
        atomicAdd(&h[v.z & 1023u], 1);
        atomicAdd(&h[v.w & 1023u], 1);
    }
    int t = nv * 4 + tid;
    if (t < cnt) atomicAdd(&h[seg[t] & 1023u], 1);
    __syncthreads();
    for (int l = tid; l < CPB; l += 512) {
        int v = b * CPB + l;
        float d = (float)(1.0 / sqrt((double)(h[l] + 1)));  // +1 self loop
        dinv[v] = d;
        z[v] = d * x[v];
    }
}

// ---------------------------------------------------------------------------
// Bucketed hop: LDS accumulate z[row] per local col, then
// t[v] = z[v] + facc;  out = mode ? d^2*t (next z) : d*t (final x).
__global__ void hop_kernel(const uint32_t* __restrict__ packed, const int* __restrict__ cursor,
                           const float* __restrict__ z, const float* __restrict__ dinv,
                           float* __restrict__ out, int mode) {
    __shared__ float facc[CPB];
    int b = blockIdx.x, tid = threadIdx.x;
    for (int l = tid; l < CPB; l += 512) facc[l] = 0.0f;
    __syncthreads();
    int cnt = cursor[b]; if (cnt > CAP) cnt = CAP;
    const uint32_t* seg = packed + (size_t)b * CAP;
    int nv = cnt >> 2;
    for (int g = tid; g < nv; g += 512) {
        uint4 v = *(const uint4*)(seg + g * 4);
        float z0 = z[v.x >> 10];
        float z1 = z[v.y >> 10];
        float z2 = z[v.z >> 10];
        float z3 = z[v.w >> 10];
        atomicAdd(&facc[v.x & 1023u], z0);
        atomicAdd(&facc[v.y & 1023u], z1);
        atomicAdd(&facc[v.z & 1023u], z2);
        atomicAdd(&facc[v.w & 1023u], z3);
    }
    int t = nv * 4 + tid;
    if (t < cnt) { uint32_t p = seg[t]; atomicAdd(&facc[p & 1023u], z[p >> 10]); }
    __syncthreads();
    for (int l = tid; l < CPB; l += 512) {
        int v = b * CPB + l;
        float tt = z[v] + facc[l];
        float d = dinv[v];
        out[v] = mode ? d * d * tt : d * tt;
    }
}

// out[g] = W * mean_{chunk g}(xf) + b
__global__ void pool_kernel(const float* __restrict__ xf,
                            const float* __restrict__ W, const float* __restrict__ b,
                            float* __restrict__ out) {
    __shared__ double sdata[256];
    int g = blockIdx.x;
    int base = g * CHUNK;
    double s = 0.0;
    for (int i = threadIdx.x; i < CHUNK; i += 256) s += (double)xf[base + i];
    sdata[threadIdx.x] = s;
    __syncthreads();
    for (int off = 128; off > 0; off >>= 1) {
        if (threadIdx.x < off) sdata[threadIdx.x] += sdata[threadIdx.x + off];
        __syncthreads();
    }
    if (threadIdx.x == 0)
        out[g] = (float)((double)W[0] * (sdata[0] / (double)CHUNK) + (double)b[0]);
}

// ---------------- fallback (push, atomics) for small ws ---------------------
__device__ __forceinline__ int load_idx(const void* ei, int is64, size_t pos) {
    if (is64) return (int)((const unsigned long long*)ei)[pos];
    return ((const int*)ei)[pos];
}

__global__ void count_kernel(const void* __restrict__ ei, const int* __restrict__ flag,
                             int* __restrict__ deg) {
    int e = blockIdx.x * blockDim.x + threadIdx.x;
    int c = load_idx(ei, flag[0], (size_t)N_EDGES + (size_t)e);
    atomicAdd(&deg[c], 1);
}

__global__ void dinv_kernel(const int* __restrict__ deg, float* __restrict__ dinv) {
    int v = blockIdx.x * blockDim.x + threadIdx.x;
    dinv[v] = (float)(1.0 / sqrt((double)(deg[v] + 1)));
}

__global__ void prep_first2_kernel(const float* __restrict__ x, const float* __restrict__ dinv,
                                   float* __restrict__ z, float* __restrict__ acc) {
    int v = blockIdx.x * blockDim.x + threadIdx.x;
    float t = dinv[v] * x[v];
    z[v] = t;
    acc[v] = t;
}

__global__ void prep_mid_kernel(const float* __restrict__ dinv,
                                float* __restrict__ z, float* __restrict__ acc) {
    int v = blockIdx.x * blockDim.x + threadIdx.x;
    float d = dinv[v];
    float t = d * d * acc[v];
    z[v] = t;
    acc[v] = t;
}

__global__ void push_kernel(const void* __restrict__ ei, const int* __restrict__ flag,
                            const float* __restrict__ z, float* __restrict__ acc) {
    int e = blockIdx.x * blockDim.x + threadIdx.x;
    int is64 = flag[0];
    int r, c;
    if (is64) {
        const unsigned long long* p = (const unsigned long long*)ei;
        r = (int)p[e];
        c = (int)p[(size_t)N_EDGES + (size_t)e];
    } else {
        const int* p = (const int*)ei;
        r = p[e];
        c = p[(size_t)N_EDGES + (size_t)e];
    }
    __hip_atomic_fetch_add(&acc[c], z[r], __ATOMIC_RELAXED, __HIP_MEMORY_SCOPE_AGENT);
}

__global__ void final_scale_kernel(const float* __restrict__ dinv,
                                   const float* __restrict__ acc, float* __restrict__ xf) {
    int v = blockIdx.x * blockDim.x + threadIdx.x;
    xf[v] = dinv[v] * acc[v];
}

extern "C" void kernel_launch(void* const* d_in, const int* in_sizes, int n_in,
                              void* d_out, int out_size, void* d_ws, size_t ws_size,
                              hipStream_t stream) {
    const float* x = (const float*)d_in[0];
    const void*  ei = d_in[1];
    const float* W = (const float*)d_in[2];
    const float* b = (const float*)d_in[3];
    float* out = (float*)d_out;

    char* ws = (char*)d_ws;
    const size_t MB4 = 4ull << 20;
    size_t off_flag   = 0;                                // 256 B
    size_t off_cursor = 256;                              // 4 KB
    size_t off_dinv   = off_cursor + NBUCKET * 4;         // 4 MB
    size_t off_za     = off_dinv + MB4;                   // 4 MB
    size_t off_zb     = off_za + MB4;                     // 4 MB
    size_t off_packed = off_zb + MB4;                     // 72 MB
    size_t needed     = off_packed + (size_t)NBUCKET * CAP * 4;

    const int TB = 256;

    if (ws_size >= needed) {
        int*      flag   = (int*)(ws + off_flag);
        int*      cursor = (int*)(ws + off_cursor);
        float*    dinv   = (float*)(ws + off_dinv);
        float*    za     = (float*)(ws + off_za);
        float*    zb     = (float*)(ws + off_zb);
        uint32_t* packed = (uint32_t*)(ws + off_packed);

        detect_kernel<<<1, TB, 0, stream>>>((const uint32_t*)ei, flag);
        zero_int_kernel<<<NBUCKET / TB, TB, 0, stream>>>(cursor);
        scatter_sort_kernel<<<NBLK_SS, TB_SS, 0, stream>>>(ei, flag, cursor, packed);
        degdinv_kernel<<<NBUCKET, 512, 0, stream>>>(packed, cursor, x, dinv, za);

        hop_kernel<<<NBUCKET, 512, 0, stream>>>(packed, cursor, za, dinv, zb, 1);
        hop_kernel<<<NBUCKET, 512, 0, stream>>>(packed, cursor, zb, dinv, za, 1);
        hop_kernel<<<NBUCKET, 512, 0, stream>>>(packed, cursor, za, dinv, zb, 1);
        hop_kernel<<<NBUCKET, 512, 0, stream>>>(packed, cursor, zb, dinv, za, 0);

        pool_kernel<<<N_GRAPHS, TB, 0, stream>>>(za, W, b, out);
    } else {
        // Fallback: push-based with atomics.
        int*   flag = (int*)ws;
        float* dinv = (float*)(ws + 256);
        float* za   = (float*)(ws + 256 + MB4);
        float* zb   = (float*)(ws + 256 + 2 * MB4);
        int*   deg  = (int*)(ws + 256 + 3 * MB4);

        detect_kernel<<<1, TB, 0, stream>>>((const uint32_t*)ei, flag);
        zero_int_kernel<<<N_NODES / TB, TB, 0, stream>>>(deg);
        count_kernel<<<N_EDGES / TB, TB, 0, stream>>>(ei, flag, deg);
        dinv_kernel<<<N_NODES / TB, TB, 0, stream>>>(deg, dinv);

        prep_first2_kernel<<<N_NODES / TB, TB, 0, stream>>>(x, dinv, za, zb);
        push_kernel<<<N_EDGES / TB, TB, 0, stream>>>(ei, flag, za, zb);
        for (int h = 1; h < K_HOPS; ++h) {
            prep_mid_kernel<<<N_NODES / TB, TB, 0, stream>>>(dinv, za, zb);
            push_kernel<<<N_EDGES / TB, TB, 0, stream>>>(ei, flag, za, zb);
        }
        final_scale_kernel<<<N_NODES / TB, TB, 0, stream>>>(dinv, zb, za);
        pool_kernel<<<N_GRAPHS, TB, 0, stream>>>(za, W, b, out);
    }
}